// Round 3
// baseline (466.152 us; speedup 1.0000x reference)
//
#include <hip/hip_runtime.h>
#include <hip/hip_bf16.h>
#include <math.h>

// ---------------------------------------------------------------------------
// ClusteringModule: e = (z@W1+b1)@W2+b2 ; s = rownorm(1/(1+||e-c||)) ; c=argmax
// Round 6: GEMM1 = 128x128 tile, 4 waves of 64x64 (32x32x16 MFMA, r5-verified
// layout), A(h,l) staged in 32KB LDS dbuf via global_load_lds, B(h,l) read
// DIRECT global->VGPR (L1/L2-served). launch_bounds(256,4) + K-split-8 ->
// 1024 blocks -> 4 blocks/CU = 16 waves/CU (4/SIMD). LDS traffic drops below
// the MFMA floor; waves/SIMD restored to the r3 level that hides latency.
// Runtime fallback to K-split-4 if workspace is too small for 8 partials.
// ---------------------------------------------------------------------------

typedef __bf16 bf16x8 __attribute__((ext_vector_type(8)));
typedef float  f32x4  __attribute__((ext_vector_type(4)));
typedef float  f32x16 __attribute__((ext_vector_type(16)));
typedef unsigned short ushort8 __attribute__((ext_vector_type(8)));

#define MROWS 2048
#define KDIM  12000
#define N1    1024
#define N2    64
#define NCL   100

constexpr int KT = 375;          // k-tiles of 32
constexpr int MT = 16;           // m-tiles of 128
constexpr int NT = 8;            // n-tiles of 128
constexpr int TILE_E = 4096;     // 128x32 bf16 elems per tile (8192 B)
constexpr long long AE = (long long)MT * KT * TILE_E;
constexpr long long BE = (long long)NT * KT * TILE_E;

__device__ __forceinline__ unsigned short f2bf(float f) {
  unsigned int u = __float_as_uint(f);
  return (unsigned short)((u + 0x7FFFu + ((u >> 16) & 1u)) >> 16);   // RNE
}
__device__ __forceinline__ float bf2f(unsigned short h) {
  return __uint_as_float(((unsigned int)h) << 16);
}

__device__ __forceinline__ void gl_lds16(const unsigned short* g, unsigned short* l) {
  __builtin_amdgcn_global_load_lds((const __attribute__((address_space(1))) void*)g,
                                   (__attribute__((address_space(3))) void*)l, 16, 0, 0);
}

// ------------------- pre-split: z -> Ah/Al (transpose-free) -----------------
__global__ __launch_bounds__(256) void split_z(const float* __restrict__ z,
                                               unsigned short* __restrict__ Ah,
                                               unsigned short* __restrict__ Al) {
  const int t  = threadIdx.x;
  const int kt = blockIdx.x, mt = blockIdx.y;
  const long long tb = (long long)(mt * KT + kt) * TILE_E;
#pragma unroll
  for (int i = 0; i < 2; ++i) {
    const int idx = i * 256 + t;           // 0..511
    const int r   = idx >> 2;              // 0..127
    const int k16 = idx & 3;               // 0..3
    const float* src = z + (long long)(mt * 128 + r) * KDIM + kt * 32 + k16 * 8;
    const float4 v0 = *(const float4*)src;
    const float4 v1 = *(const float4*)(src + 4);
    const float vv[8] = {v0.x, v0.y, v0.z, v0.w, v1.x, v1.y, v1.z, v1.w};
    ushort8 h, l;
#pragma unroll
    for (int j = 0; j < 8; ++j) {
      const unsigned short hs = f2bf(vv[j]);
      h[j] = hs; l[j] = f2bf(vv[j] - bf2f(hs));
    }
    const long long o = tb + (long long)(k16 * 128 + r) * 8;
    *(ushort8*)&Ah[o] = h;
    *(ushort8*)&Al[o] = l;
  }
}

// --------------------- pre-split: W1 -> Bh/Bl (transposed) ------------------
__global__ __launch_bounds__(256) void split_w(const float* __restrict__ W1,
                                               unsigned short* __restrict__ Bh,
                                               unsigned short* __restrict__ Bl) {
  __shared__ float tile[32][129];
  const int t = threadIdx.x;
  const int kt = blockIdx.x, nt = blockIdx.y;
  const float* src = W1 + (long long)(kt * 32) * N1 + nt * 128;
#pragma unroll
  for (int i = 0; i < 4; ++i) {
    const int idx = i * 256 + t, r = idx >> 5, c4 = idx & 31;
    const float4 v = *(const float4*)(src + (long long)r * N1 + c4 * 4);
    tile[r][c4 * 4 + 0] = v.x; tile[r][c4 * 4 + 1] = v.y;
    tile[r][c4 * 4 + 2] = v.z; tile[r][c4 * 4 + 3] = v.w;
  }
  __syncthreads();
  const long long tb = (long long)(nt * KT + kt) * TILE_E;
#pragma unroll
  for (int i = 0; i < 2; ++i) {
    const int q = i * 256 + t, k16 = q >> 7, col = q & 127;
    ushort8 h, l;
#pragma unroll
    for (int j = 0; j < 8; ++j) {
      const float f = tile[k16 * 8 + j][col];
      const unsigned short hs = f2bf(f);
      h[j] = hs; l[j] = f2bf(f - bf2f(hs));
    }
    *(ushort8*)&Bh[tb + q * 8] = h;
    *(ushort8*)&Bl[tb + q * 8] = l;
  }
}

// ----------------------- GEMM1: split-3 bf16 MFMA ---------------------------
// 128x128 tile, BK=32, 4 waves x (64x64) via 32x32x16 MFMA.
// A in LDS (32KB dbuf, global_load_lds); B direct global->VGPR.
// grid = nks*128 blocks of 256 thr; 4 blocks/CU = 16 waves/CU.
__global__ __launch_bounds__(256, 4)
void gemm_split3(const unsigned short* __restrict__ Ah, const unsigned short* __restrict__ Al,
                 const unsigned short* __restrict__ Bh, const unsigned short* __restrict__ Bl,
                 const float* __restrict__ b1, float* __restrict__ e1p, int qsteps)
{
  __shared__ unsigned short lds[2][2][TILE_E];   // 32 KB
  const int t = threadIdx.x, lane = t & 63, w = t >> 6;   // w: 0..3
  const int wr = w >> 1, wc = w & 1;                      // wave tile: 64x64
  const int bid = blockIdx.x;
  const int cpx = (int)gridDim.x >> 3;           // blocks per XCD chunk
  const int wg  = (bid & 7) * cpx + (bid >> 3);  // XCD chunked swizzle
  const int ks = wg >> 7;                        // 128 blocks per ks slice
  const int mt = (wg >> 3) & 15;
  const int nt = wg & 7;
  const int s0 = ks * qsteps;
  const int nst = min(qsteps, KT - s0);

  const unsigned short* ga0 = Ah + (long long)(mt * KT + s0) * TILE_E;
  const unsigned short* ga1 = Al + (long long)(mt * KT + s0) * TILE_E;
  const unsigned short* gbh = Bh + (long long)(nt * KT + s0) * TILE_E;
  const unsigned short* gbl = Bl + (long long)(nt * KT + s0) * TILE_E;

  const int row_l = lane & 31;        // row/col within 32x32 fragment
  const int kg    = lane >> 5;        // k-group: k = kg*8 + j within K16

  // per-lane, step-invariant B fragment offsets (in shorts)
  int offB[2][2];
#pragma unroll
  for (int kh = 0; kh < 2; ++kh)
#pragma unroll
    for (int nf = 0; nf < 2; ++nf)
      offB[kh][nf] = ((kh * 2 + kg) * 128 + wc * 64 + nf * 32 + row_l) * 8;

  auto stage = [&](int buf, int s) {   // A only: 4 x gl_lds16 = 16 KB/block
    const long long so = (long long)s * TILE_E + t * 8;
    gl_lds16(ga0 + so,        &lds[buf][0][t * 8]);
    gl_lds16(ga0 + so + 2048, &lds[buf][0][2048 + t * 8]);
    gl_lds16(ga1 + so,        &lds[buf][1][t * 8]);
    gl_lds16(ga1 + so + 2048, &lds[buf][1][2048 + t * 8]);
  };

  f32x16 acc[2][2] = {};

  stage(0, 0);
  __syncthreads();
  int buf = 0;
  for (int s = 0; s < nst; ++s) {
    // B fragments direct from global. Issued BEFORE the next-tile stage so the
    // compiler's waitcnt for B-use leaves the A-prefetch gl_lds outstanding.
    bf16x8 bh[2][2], bl[2][2];
    const unsigned short* pbh = gbh + (long long)s * TILE_E;
    const unsigned short* pbl = gbl + (long long)s * TILE_E;
#pragma unroll
    for (int kh = 0; kh < 2; ++kh)
#pragma unroll
      for (int nf = 0; nf < 2; ++nf) {
        bh[kh][nf] = *(const bf16x8*)(pbh + offB[kh][nf]);
        bl[kh][nf] = *(const bf16x8*)(pbl + offB[kh][nf]);
      }
    if (s + 1 < nst) stage(buf ^ 1, s + 1);

    __builtin_amdgcn_s_setprio(1);
#pragma unroll
    for (int kh = 0; kh < 2; ++kh) {
      const int k16 = kh * 2 + kg;
      // A-high fragments (re-read per kh scope to bound VGPR liveness)
      const bf16x8 a0 = *(const bf16x8*)&lds[buf][0][k16 * 1024 + (wr * 64 +  0 + row_l) * 8];
      const bf16x8 a1 = *(const bf16x8*)&lds[buf][0][k16 * 1024 + (wr * 64 + 32 + row_l) * 8];
      // pass 1: ah x bh
      acc[0][0] = __builtin_amdgcn_mfma_f32_32x32x16_bf16(a0, bh[kh][0], acc[0][0], 0, 0, 0);
      acc[0][1] = __builtin_amdgcn_mfma_f32_32x32x16_bf16(a0, bh[kh][1], acc[0][1], 0, 0, 0);
      acc[1][0] = __builtin_amdgcn_mfma_f32_32x32x16_bf16(a1, bh[kh][0], acc[1][0], 0, 0, 0);
      acc[1][1] = __builtin_amdgcn_mfma_f32_32x32x16_bf16(a1, bh[kh][1], acc[1][1], 0, 0, 0);
      // pass 2: ah x bl
      acc[0][0] = __builtin_amdgcn_mfma_f32_32x32x16_bf16(a0, bl[kh][0], acc[0][0], 0, 0, 0);
      acc[0][1] = __builtin_amdgcn_mfma_f32_32x32x16_bf16(a0, bl[kh][1], acc[0][1], 0, 0, 0);
      acc[1][0] = __builtin_amdgcn_mfma_f32_32x32x16_bf16(a1, bl[kh][0], acc[1][0], 0, 0, 0);
      acc[1][1] = __builtin_amdgcn_mfma_f32_32x32x16_bf16(a1, bl[kh][1], acc[1][1], 0, 0, 0);
      // pass 3: al x bh
      const bf16x8 l0 = *(const bf16x8*)&lds[buf][1][k16 * 1024 + (wr * 64 +  0 + row_l) * 8];
      const bf16x8 l1 = *(const bf16x8*)&lds[buf][1][k16 * 1024 + (wr * 64 + 32 + row_l) * 8];
      acc[0][0] = __builtin_amdgcn_mfma_f32_32x32x16_bf16(l0, bh[kh][0], acc[0][0], 0, 0, 0);
      acc[0][1] = __builtin_amdgcn_mfma_f32_32x32x16_bf16(l0, bh[kh][1], acc[0][1], 0, 0, 0);
      acc[1][0] = __builtin_amdgcn_mfma_f32_32x32x16_bf16(l1, bh[kh][0], acc[1][0], 0, 0, 0);
      acc[1][1] = __builtin_amdgcn_mfma_f32_32x32x16_bf16(l1, bh[kh][1], acc[1][1], 0, 0, 0);
    }
    __builtin_amdgcn_s_setprio(0);
    __syncthreads();
    buf ^= 1;
  }

  // Epilogue: 32x32 C/D layout col=lane&31, row=(reg&3)+8*(reg>>2)+4*(lane>>5)
  float* eo = e1p + (long long)ks * MROWS * N1;
#pragma unroll
  for (int mf = 0; mf < 2; ++mf) {
#pragma unroll
    for (int nf = 0; nf < 2; ++nf) {
      const int col = nt * 128 + wc * 64 + nf * 32 + row_l;
      const float bias = (ks == 0) ? b1[col] : 0.0f;
#pragma unroll
      for (int r = 0; r < 16; ++r) {
        const int row = mt * 128 + wr * 64 + mf * 32 + (r & 3) + 8 * (r >> 2) + 4 * kg;
        eo[(long long)row * N1 + col] = acc[mf][nf][r] + bias;
      }
    }
  }
}

// ------------------------ GEMM2 + distances + argmax ------------------------
constexpr int RPB = 8;

__global__ __launch_bounds__(256, 2)
void head_kernel(const float* __restrict__ e1, const float* __restrict__ W2,
                 const float* __restrict__ b2, const float* __restrict__ cents,
                 float* __restrict__ eOut, float* __restrict__ sOut,
                 float* __restrict__ cOut, int nks)
{
  __shared__ float cent_s[NCL * 65];
  __shared__ float e_s[RPB][N2 + 4];
  const int t = threadIdx.x;
  const int r0 = blockIdx.x * RPB;
  constexpr long long PS = (long long)MROWS * N1;

  for (int i = t; i < NCL * N2; i += 256) {
    const int c = i >> 6, d = i & 63;
    cent_s[c * 65 + d] = cents[i];
  }

  const int n = t & 63;
  const int rq = t >> 6;
  float acc0 = 0.f, acc1 = 0.f;
  const float* e1r0 = e1 + (long long)(r0 + rq) * N1;
  const float* e1r1 = e1 + (long long)(r0 + rq + 4) * N1;
  for (int k = 0; k < N1; k += 4) {
    f32x4 x0 = *(const f32x4*)(e1r0 + k);
    f32x4 x1 = *(const f32x4*)(e1r1 + k);
    for (int p = 1; p < nks; ++p) {
      x0 += *(const f32x4*)(e1r0 + p * PS + k);
      x1 += *(const f32x4*)(e1r1 + p * PS + k);
    }
    const float w0 = W2[(k + 0) * N2 + n];
    const float w1 = W2[(k + 1) * N2 + n];
    const float w2 = W2[(k + 2) * N2 + n];
    const float w3 = W2[(k + 3) * N2 + n];
    acc0 = fmaf(x0[0], w0, acc0); acc0 = fmaf(x0[1], w1, acc0);
    acc0 = fmaf(x0[2], w2, acc0); acc0 = fmaf(x0[3], w3, acc0);
    acc1 = fmaf(x1[0], w0, acc1); acc1 = fmaf(x1[1], w1, acc1);
    acc1 = fmaf(x1[2], w2, acc1); acc1 = fmaf(x1[3], w3, acc1);
  }
  acc0 += b2[n]; acc1 += b2[n];
  eOut[(long long)(r0 + rq) * N2 + n]     = acc0;
  eOut[(long long)(r0 + rq + 4) * N2 + n] = acc1;
  e_s[rq][n]     = acc0;
  e_s[rq + 4][n] = acc1;
  __syncthreads();

  const int row = t >> 5;
  const int ci  = t & 31;
  float sum = 0.f, bestv = -1.f;
  int bestc = 0;
  float sv[4] = {0.f, 0.f, 0.f, 0.f};
#pragma unroll
  for (int j = 0; j < 4; ++j) {
    const int c = ci + 32 * j;
    if (c < NCL) {
      float d2 = 0.f;
#pragma unroll 8
      for (int d = 0; d < N2; ++d) {
        const float diff = e_s[row][d] - cent_s[c * 65 + d];
        d2 = fmaf(diff, diff, d2);
      }
      const float su = 1.0f / (1.0f + sqrtf(d2));
      sv[j] = su; sum += su;
      if (su > bestv) { bestv = su; bestc = c; }
    }
  }
#pragma unroll
  for (int off = 1; off < 32; off <<= 1) {
    sum += __shfl_xor(sum, off);
    const float ov = __shfl_xor(bestv, off);
    const int   oc = __shfl_xor(bestc, off);
    if (ov > bestv || (ov == bestv && oc < bestc)) { bestv = ov; bestc = oc; }
  }
  const float inv = 1.0f / sum;
#pragma unroll
  for (int j = 0; j < 4; ++j) {
    const int c = ci + 32 * j;
    if (c < NCL) sOut[(long long)(r0 + row) * NCL + c] = sv[j] * inv;
  }
  if (ci == 0) cOut[r0 + row] = (float)bestc;
}

// --------------------------------- launch -----------------------------------
extern "C" void kernel_launch(void* const* d_in, const int* in_sizes, int n_in,
                              void* d_out, int out_size, void* d_ws, size_t ws_size,
                              hipStream_t stream)
{
  const float* z     = (const float*)d_in[0];
  const float* W1    = (const float*)d_in[1];
  const float* b1    = (const float*)d_in[2];
  const float* W2    = (const float*)d_in[3];
  const float* b2    = (const float*)d_in[4];
  const float* cents = (const float*)d_in[5];
  float* out  = (float*)d_out;
  float* eOut = out;
  float* sOut = out + MROWS * N2;
  float* cOut = out + MROWS * N2 + MROWS * NCL;

  unsigned short* Ah = (unsigned short*)d_ws;
  unsigned short* Al = Ah + AE;
  unsigned short* Bh = Al + AE;
  unsigned short* Bl = Bh + BE;
  float* e1p = (float*)(Bl + BE);

  // 8 e1p partials need ~215 MB of workspace; fall back to 4 if unavailable.
  const unsigned long long need8 =
      (unsigned long long)(2 * AE + 2 * BE) * 2ull + 8ull * MROWS * N1 * 4ull;
  const int nks = (ws_size == 0 || ws_size >= need8) ? 8 : 4;
  const int q = (KT + nks - 1) / nks;   // 47 (nks=8) or 94 (nks=4)

  split_z<<<dim3(KT, MT), 256, 0, stream>>>(z, Ah, Al);
  split_w<<<dim3(KT, NT), 256, 0, stream>>>(W1, Bh, Bl);
  gemm_split3<<<nks * 128, 256, 0, stream>>>(Ah, Al, Bh, Bl, b1, e1p, q);
  head_kernel<<<MROWS / RPB, 256, 0, stream>>>(e1p, W2, b2, cents, eOut, sOut, cOut, nks);
}

// Round 4
// 234.416 us; speedup vs baseline: 1.9886x; 1.9886x over previous
//
#include <hip/hip_runtime.h>
#include <hip/hip_bf16.h>
#include <math.h>

// ---------------------------------------------------------------------------
// ClusteringModule: e = (z@W1+b1)@W2+b2 ; s = rownorm(1/(1+||e-c||)) ; c=argmax
// Round 7: split_z / split_w / gemm_split3 UNCHANGED from r6 (B-direct,
// A-in-LDS, 4 blocks/CU). head_kernel rewritten: cooperative LDS reduction of
// the NKS e1 partials (compile-time-unrolled, coalesced f32x4), GEMM2 from
// LDS broadcast. Fixes r6's 280us latency-bound head (runtime-trip loop).
// ---------------------------------------------------------------------------

typedef __bf16 bf16x8 __attribute__((ext_vector_type(8)));
typedef float  f32x4  __attribute__((ext_vector_type(4)));
typedef float  f32x16 __attribute__((ext_vector_type(16)));
typedef unsigned short ushort8 __attribute__((ext_vector_type(8)));

#define MROWS 2048
#define KDIM  12000
#define N1    1024
#define N2    64
#define NCL   100

constexpr int KT = 375;          // k-tiles of 32
constexpr int MT = 16;           // m-tiles of 128
constexpr int NT = 8;            // n-tiles of 128
constexpr int TILE_E = 4096;     // 128x32 bf16 elems per tile (8192 B)
constexpr long long AE = (long long)MT * KT * TILE_E;
constexpr long long BE = (long long)NT * KT * TILE_E;

__device__ __forceinline__ unsigned short f2bf(float f) {
  unsigned int u = __float_as_uint(f);
  return (unsigned short)((u + 0x7FFFu + ((u >> 16) & 1u)) >> 16);   // RNE
}
__device__ __forceinline__ float bf2f(unsigned short h) {
  return __uint_as_float(((unsigned int)h) << 16);
}

__device__ __forceinline__ void gl_lds16(const unsigned short* g, unsigned short* l) {
  __builtin_amdgcn_global_load_lds((const __attribute__((address_space(1))) void*)g,
                                   (__attribute__((address_space(3))) void*)l, 16, 0, 0);
}

// ------------------- pre-split: z -> Ah/Al (transpose-free) -----------------
__global__ __launch_bounds__(256) void split_z(const float* __restrict__ z,
                                               unsigned short* __restrict__ Ah,
                                               unsigned short* __restrict__ Al) {
  const int t  = threadIdx.x;
  const int kt = blockIdx.x, mt = blockIdx.y;
  const long long tb = (long long)(mt * KT + kt) * TILE_E;
#pragma unroll
  for (int i = 0; i < 2; ++i) {
    const int idx = i * 256 + t;           // 0..511
    const int r   = idx >> 2;              // 0..127
    const int k16 = idx & 3;               // 0..3
    const float* src = z + (long long)(mt * 128 + r) * KDIM + kt * 32 + k16 * 8;
    const float4 v0 = *(const float4*)src;
    const float4 v1 = *(const float4*)(src + 4);
    const float vv[8] = {v0.x, v0.y, v0.z, v0.w, v1.x, v1.y, v1.z, v1.w};
    ushort8 h, l;
#pragma unroll
    for (int j = 0; j < 8; ++j) {
      const unsigned short hs = f2bf(vv[j]);
      h[j] = hs; l[j] = f2bf(vv[j] - bf2f(hs));
    }
    const long long o = tb + (long long)(k16 * 128 + r) * 8;
    *(ushort8*)&Ah[o] = h;
    *(ushort8*)&Al[o] = l;
  }
}

// --------------------- pre-split: W1 -> Bh/Bl (transposed) ------------------
__global__ __launch_bounds__(256) void split_w(const float* __restrict__ W1,
                                               unsigned short* __restrict__ Bh,
                                               unsigned short* __restrict__ Bl) {
  __shared__ float tile[32][129];
  const int t = threadIdx.x;
  const int kt = blockIdx.x, nt = blockIdx.y;
  const float* src = W1 + (long long)(kt * 32) * N1 + nt * 128;
#pragma unroll
  for (int i = 0; i < 4; ++i) {
    const int idx = i * 256 + t, r = idx >> 5, c4 = idx & 31;
    const float4 v = *(const float4*)(src + (long long)r * N1 + c4 * 4);
    tile[r][c4 * 4 + 0] = v.x; tile[r][c4 * 4 + 1] = v.y;
    tile[r][c4 * 4 + 2] = v.z; tile[r][c4 * 4 + 3] = v.w;
  }
  __syncthreads();
  const long long tb = (long long)(nt * KT + kt) * TILE_E;
#pragma unroll
  for (int i = 0; i < 2; ++i) {
    const int q = i * 256 + t, k16 = q >> 7, col = q & 127;
    ushort8 h, l;
#pragma unroll
    for (int j = 0; j < 8; ++j) {
      const float f = tile[k16 * 8 + j][col];
      const unsigned short hs = f2bf(f);
      h[j] = hs; l[j] = f2bf(f - bf2f(hs));
    }
    *(ushort8*)&Bh[tb + q * 8] = h;
    *(ushort8*)&Bl[tb + q * 8] = l;
  }
}

// ----------------------- GEMM1: split-3 bf16 MFMA ---------------------------
// 128x128 tile, BK=32, 4 waves x (64x64) via 32x32x16 MFMA.
// A in LDS (32KB dbuf, global_load_lds); B direct global->VGPR.
// grid = nks*128 blocks of 256 thr; 4 blocks/CU = 16 waves/CU.
__global__ __launch_bounds__(256, 4)
void gemm_split3(const unsigned short* __restrict__ Ah, const unsigned short* __restrict__ Al,
                 const unsigned short* __restrict__ Bh, const unsigned short* __restrict__ Bl,
                 const float* __restrict__ b1, float* __restrict__ e1p, int qsteps)
{
  __shared__ unsigned short lds[2][2][TILE_E];   // 32 KB
  const int t = threadIdx.x, lane = t & 63, w = t >> 6;   // w: 0..3
  const int wr = w >> 1, wc = w & 1;                      // wave tile: 64x64
  const int bid = blockIdx.x;
  const int cpx = (int)gridDim.x >> 3;           // blocks per XCD chunk
  const int wg  = (bid & 7) * cpx + (bid >> 3);  // XCD chunked swizzle
  const int ks = wg >> 7;                        // 128 blocks per ks slice
  const int mt = (wg >> 3) & 15;
  const int nt = wg & 7;
  const int s0 = ks * qsteps;
  const int nst = min(qsteps, KT - s0);

  const unsigned short* ga0 = Ah + (long long)(mt * KT + s0) * TILE_E;
  const unsigned short* ga1 = Al + (long long)(mt * KT + s0) * TILE_E;
  const unsigned short* gbh = Bh + (long long)(nt * KT + s0) * TILE_E;
  const unsigned short* gbl = Bl + (long long)(nt * KT + s0) * TILE_E;

  const int row_l = lane & 31;        // row/col within 32x32 fragment
  const int kg    = lane >> 5;        // k-group: k = kg*8 + j within K16

  // per-lane, step-invariant B fragment offsets (in shorts)
  int offB[2][2];
#pragma unroll
  for (int kh = 0; kh < 2; ++kh)
#pragma unroll
    for (int nf = 0; nf < 2; ++nf)
      offB[kh][nf] = ((kh * 2 + kg) * 128 + wc * 64 + nf * 32 + row_l) * 8;

  auto stage = [&](int buf, int s) {   // A only: 4 x gl_lds16 = 16 KB/block
    const long long so = (long long)s * TILE_E + t * 8;
    gl_lds16(ga0 + so,        &lds[buf][0][t * 8]);
    gl_lds16(ga0 + so + 2048, &lds[buf][0][2048 + t * 8]);
    gl_lds16(ga1 + so,        &lds[buf][1][t * 8]);
    gl_lds16(ga1 + so + 2048, &lds[buf][1][2048 + t * 8]);
  };

  f32x16 acc[2][2] = {};

  stage(0, 0);
  __syncthreads();
  int buf = 0;
  for (int s = 0; s < nst; ++s) {
    // B fragments direct from global. Issued BEFORE the next-tile stage so the
    // compiler's waitcnt for B-use leaves the A-prefetch gl_lds outstanding.
    bf16x8 bh[2][2], bl[2][2];
    const unsigned short* pbh = gbh + (long long)s * TILE_E;
    const unsigned short* pbl = gbl + (long long)s * TILE_E;
#pragma unroll
    for (int kh = 0; kh < 2; ++kh)
#pragma unroll
      for (int nf = 0; nf < 2; ++nf) {
        bh[kh][nf] = *(const bf16x8*)(pbh + offB[kh][nf]);
        bl[kh][nf] = *(const bf16x8*)(pbl + offB[kh][nf]);
      }
    if (s + 1 < nst) stage(buf ^ 1, s + 1);

    __builtin_amdgcn_s_setprio(1);
#pragma unroll
    for (int kh = 0; kh < 2; ++kh) {
      const int k16 = kh * 2 + kg;
      const bf16x8 a0 = *(const bf16x8*)&lds[buf][0][k16 * 1024 + (wr * 64 +  0 + row_l) * 8];
      const bf16x8 a1 = *(const bf16x8*)&lds[buf][0][k16 * 1024 + (wr * 64 + 32 + row_l) * 8];
      acc[0][0] = __builtin_amdgcn_mfma_f32_32x32x16_bf16(a0, bh[kh][0], acc[0][0], 0, 0, 0);
      acc[0][1] = __builtin_amdgcn_mfma_f32_32x32x16_bf16(a0, bh[kh][1], acc[0][1], 0, 0, 0);
      acc[1][0] = __builtin_amdgcn_mfma_f32_32x32x16_bf16(a1, bh[kh][0], acc[1][0], 0, 0, 0);
      acc[1][1] = __builtin_amdgcn_mfma_f32_32x32x16_bf16(a1, bh[kh][1], acc[1][1], 0, 0, 0);
      acc[0][0] = __builtin_amdgcn_mfma_f32_32x32x16_bf16(a0, bl[kh][0], acc[0][0], 0, 0, 0);
      acc[0][1] = __builtin_amdgcn_mfma_f32_32x32x16_bf16(a0, bl[kh][1], acc[0][1], 0, 0, 0);
      acc[1][0] = __builtin_amdgcn_mfma_f32_32x32x16_bf16(a1, bl[kh][0], acc[1][0], 0, 0, 0);
      acc[1][1] = __builtin_amdgcn_mfma_f32_32x32x16_bf16(a1, bl[kh][1], acc[1][1], 0, 0, 0);
      const bf16x8 l0 = *(const bf16x8*)&lds[buf][1][k16 * 1024 + (wr * 64 +  0 + row_l) * 8];
      const bf16x8 l1 = *(const bf16x8*)&lds[buf][1][k16 * 1024 + (wr * 64 + 32 + row_l) * 8];
      acc[0][0] = __builtin_amdgcn_mfma_f32_32x32x16_bf16(l0, bh[kh][0], acc[0][0], 0, 0, 0);
      acc[0][1] = __builtin_amdgcn_mfma_f32_32x32x16_bf16(l0, bh[kh][1], acc[0][1], 0, 0, 0);
      acc[1][0] = __builtin_amdgcn_mfma_f32_32x32x16_bf16(l1, bh[kh][0], acc[1][0], 0, 0, 0);
      acc[1][1] = __builtin_amdgcn_mfma_f32_32x32x16_bf16(l1, bh[kh][1], acc[1][1], 0, 0, 0);
    }
    __builtin_amdgcn_s_setprio(0);
    __syncthreads();
    buf ^= 1;
  }

  // Epilogue: 32x32 C/D layout col=lane&31, row=(reg&3)+8*(reg>>2)+4*(lane>>5)
  float* eo = e1p + (long long)ks * MROWS * N1;
#pragma unroll
  for (int mf = 0; mf < 2; ++mf) {
#pragma unroll
    for (int nf = 0; nf < 2; ++nf) {
      const int col = nt * 128 + wc * 64 + nf * 32 + row_l;
      const float bias = (ks == 0) ? b1[col] : 0.0f;
#pragma unroll
      for (int r = 0; r < 16; ++r) {
        const int row = mt * 128 + wr * 64 + mf * 32 + (r & 3) + 8 * (r >> 2) + 4 * kg;
        eo[(long long)row * N1 + col] = acc[mf][nf][r] + bias;
      }
    }
  }
}

// ------------------------ GEMM2 + distances + argmax ------------------------
// Cooperative LDS reduction of NKS partials (compile-time unrolled), GEMM2
// from LDS broadcast, then distances + argmax.
constexpr int RPB = 8;

template <int NKS>
__global__ __launch_bounds__(256, 2)
void head_kernel(const float* __restrict__ e1, const float* __restrict__ W2,
                 const float* __restrict__ b2, const float* __restrict__ cents,
                 float* __restrict__ eOut, float* __restrict__ sOut,
                 float* __restrict__ cOut)
{
  __shared__ float e_red[RPB][N1];        // 32 KB: reduced e1 rows
  __shared__ float cent_s[NCL * 65];      // 26 KB
  __shared__ float e_s[RPB][N2 + 4];
  const int t = threadIdx.x;
  const int r0 = blockIdx.x * RPB;
  constexpr long long PS = (long long)MROWS * N1;

  for (int i = t; i < NCL * N2; i += 256) {
    const int c = i >> 6, d = i & 63;
    cent_s[c * 65 + d] = cents[i];
  }

  // phase 1: reduce NKS partials into e_red. 2048 f32x4 per block; each
  // thread owns 8 f32x4 positions x NKS independent loads (coalesced 1KB/wave).
#pragma unroll
  for (int v = 0; v < 8; ++v) {
    const int idx = v * 256 + t;          // 0..2047
    const int row = idx >> 8;             // 0..7
    const int c4  = idx & 255;            // f32x4 slot within row
    const float* src = e1 + (long long)(r0 + row) * N1 + c4 * 4;
    f32x4 x = *(const f32x4*)src;
#pragma unroll
    for (int p = 1; p < NKS; ++p) x += *(const f32x4*)(src + (long long)p * PS);
    *(f32x4*)&e_red[row][c4 * 4] = x;
  }
  __syncthreads();

  // phase 2: GEMM2 from LDS (wave-uniform broadcast reads, conflict-free)
  const int n = t & 63;
  const int rq = t >> 6;
  float acc0 = 0.f, acc1 = 0.f;
  for (int k = 0; k < N1; k += 4) {
    const f32x4 x0 = *(const f32x4*)&e_red[rq][k];
    const f32x4 x1 = *(const f32x4*)&e_red[rq + 4][k];
    const float w0 = W2[(k + 0) * N2 + n];
    const float w1 = W2[(k + 1) * N2 + n];
    const float w2 = W2[(k + 2) * N2 + n];
    const float w3 = W2[(k + 3) * N2 + n];
    acc0 = fmaf(x0[0], w0, acc0); acc0 = fmaf(x0[1], w1, acc0);
    acc0 = fmaf(x0[2], w2, acc0); acc0 = fmaf(x0[3], w3, acc0);
    acc1 = fmaf(x1[0], w0, acc1); acc1 = fmaf(x1[1], w1, acc1);
    acc1 = fmaf(x1[2], w2, acc1); acc1 = fmaf(x1[3], w3, acc1);
  }
  acc0 += b2[n]; acc1 += b2[n];
  eOut[(long long)(r0 + rq) * N2 + n]     = acc0;
  eOut[(long long)(r0 + rq + 4) * N2 + n] = acc1;
  e_s[rq][n]     = acc0;
  e_s[rq + 4][n] = acc1;
  __syncthreads();

  // phase 3: distances + row-softmax-normalize + argmax
  const int row = t >> 5;
  const int ci  = t & 31;
  float sum = 0.f, bestv = -1.f;
  int bestc = 0;
  float sv[4] = {0.f, 0.f, 0.f, 0.f};
#pragma unroll
  for (int j = 0; j < 4; ++j) {
    const int c = ci + 32 * j;
    if (c < NCL) {
      float d2 = 0.f;
#pragma unroll 8
      for (int d = 0; d < N2; ++d) {
        const float diff = e_s[row][d] - cent_s[c * 65 + d];
        d2 = fmaf(diff, diff, d2);
      }
      const float su = 1.0f / (1.0f + sqrtf(d2));
      sv[j] = su; sum += su;
      if (su > bestv) { bestv = su; bestc = c; }
    }
  }
#pragma unroll
  for (int off = 1; off < 32; off <<= 1) {
    sum += __shfl_xor(sum, off);
    const float ov = __shfl_xor(bestv, off);
    const int   oc = __shfl_xor(bestc, off);
    if (ov > bestv || (ov == bestv && oc < bestc)) { bestv = ov; bestc = oc; }
  }
  const float inv = 1.0f / sum;
#pragma unroll
  for (int j = 0; j < 4; ++j) {
    const int c = ci + 32 * j;
    if (c < NCL) sOut[(long long)(r0 + row) * NCL + c] = sv[j] * inv;
  }
  if (ci == 0) cOut[r0 + row] = (float)bestc;
}

// --------------------------------- launch -----------------------------------
extern "C" void kernel_launch(void* const* d_in, const int* in_sizes, int n_in,
                              void* d_out, int out_size, void* d_ws, size_t ws_size,
                              hipStream_t stream)
{
  const float* z     = (const float*)d_in[0];
  const float* W1    = (const float*)d_in[1];
  const float* b1    = (const float*)d_in[2];
  const float* W2    = (const float*)d_in[3];
  const float* b2    = (const float*)d_in[4];
  const float* cents = (const float*)d_in[5];
  float* out  = (float*)d_out;
  float* eOut = out;
  float* sOut = out + MROWS * N2;
  float* cOut = out + MROWS * N2 + MROWS * NCL;

  unsigned short* Ah = (unsigned short*)d_ws;
  unsigned short* Al = Ah + AE;
  unsigned short* Bh = Al + AE;
  unsigned short* Bl = Bh + BE;
  float* e1p = (float*)(Bl + BE);

  // 8 e1p partials need ~215 MB of workspace; fall back to 4 if unavailable.
  const unsigned long long need8 =
      (unsigned long long)(2 * AE + 2 * BE) * 2ull + 8ull * MROWS * N1 * 4ull;
  const int nks = (ws_size == 0 || ws_size >= need8) ? 8 : 4;
  const int q = (KT + nks - 1) / nks;   // 47 (nks=8) or 94 (nks=4)

  split_z<<<dim3(KT, MT), 256, 0, stream>>>(z, Ah, Al);
  split_w<<<dim3(KT, NT), 256, 0, stream>>>(W1, Bh, Bl);
  gemm_split3<<<nks * 128, 256, 0, stream>>>(Ah, Al, Bh, Bl, b1, e1p, q);
  if (nks == 8)
    head_kernel<8><<<MROWS / RPB, 256, 0, stream>>>(e1p, W2, b2, cents, eOut, sOut, cOut);
  else
    head_kernel<4><<<MROWS / RPB, 256, 0, stream>>>(e1p, W2, b2, cents, eOut, sOut, cOut);
}

// Round 5
// 209.807 us; speedup vs baseline: 2.2218x; 1.1173x over previous
//
#include <hip/hip_runtime.h>
#include <hip/hip_bf16.h>
#include <math.h>

// ---------------------------------------------------------------------------
// ClusteringModule: e = (z@W1+b1)@W2+b2 ; s = rownorm(1/(1+||e-c||)) ; c=argmax
// Round 8: known-good composition. gemm_split3 reverted to the r3/round-0
// version (121us measured: 512x512, A+B LDS-staged via global_load_lds, 64KB
// dbuf, 2 blocks/CU, split-3 16x16x32 MFMA, K-split-4). head_kernel is the
// r7 rewrite (cooperative LDS reduction of 4 partials + GEMM2 from LDS),
// hardcoded NKS=4. split_z / split_w unchanged.
// ---------------------------------------------------------------------------

typedef __bf16 bf16x8 __attribute__((ext_vector_type(8)));
typedef float  f32x4  __attribute__((ext_vector_type(4)));
typedef unsigned short ushort8 __attribute__((ext_vector_type(8)));

#define MROWS 2048
#define KDIM  12000
#define N1    1024
#define N2    64
#define NCL   100

constexpr int KT = 375;          // k-tiles of 32
constexpr int MT = 16;           // m-tiles of 128
constexpr int NT = 8;            // n-tiles of 128
constexpr int TILE_E = 4096;     // 128x32 bf16 elems per tile (8192 B)
constexpr long long AE = (long long)MT * KT * TILE_E;
constexpr long long BE = (long long)NT * KT * TILE_E;

__device__ __forceinline__ unsigned short f2bf(float f) {
  unsigned int u = __float_as_uint(f);
  return (unsigned short)((u + 0x7FFFu + ((u >> 16) & 1u)) >> 16);   // RNE
}
__device__ __forceinline__ float bf2f(unsigned short h) {
  return __uint_as_float(((unsigned int)h) << 16);
}

__device__ __forceinline__ void gl_lds16(const unsigned short* g, unsigned short* l) {
  __builtin_amdgcn_global_load_lds((const __attribute__((address_space(1))) void*)g,
                                   (__attribute__((address_space(3))) void*)l, 16, 0, 0);
}

// ------------------- pre-split: z -> Ah/Al (transpose-free) -----------------
__global__ __launch_bounds__(256) void split_z(const float* __restrict__ z,
                                               unsigned short* __restrict__ Ah,
                                               unsigned short* __restrict__ Al) {
  const int t  = threadIdx.x;
  const int kt = blockIdx.x, mt = blockIdx.y;
  const long long tb = (long long)(mt * KT + kt) * TILE_E;
#pragma unroll
  for (int i = 0; i < 2; ++i) {
    const int idx = i * 256 + t;           // 0..511
    const int r   = idx >> 2;              // 0..127
    const int k16 = idx & 3;               // 0..3
    const float* src = z + (long long)(mt * 128 + r) * KDIM + kt * 32 + k16 * 8;
    const float4 v0 = *(const float4*)src;
    const float4 v1 = *(const float4*)(src + 4);
    const float vv[8] = {v0.x, v0.y, v0.z, v0.w, v1.x, v1.y, v1.z, v1.w};
    ushort8 h, l;
#pragma unroll
    for (int j = 0; j < 8; ++j) {
      const unsigned short hs = f2bf(vv[j]);
      h[j] = hs; l[j] = f2bf(vv[j] - bf2f(hs));
    }
    const long long o = tb + (long long)(k16 * 128 + r) * 8;
    *(ushort8*)&Ah[o] = h;
    *(ushort8*)&Al[o] = l;
  }
}

// --------------------- pre-split: W1 -> Bh/Bl (transposed) ------------------
__global__ __launch_bounds__(256) void split_w(const float* __restrict__ W1,
                                               unsigned short* __restrict__ Bh,
                                               unsigned short* __restrict__ Bl) {
  __shared__ float tile[32][129];
  const int t = threadIdx.x;
  const int kt = blockIdx.x, nt = blockIdx.y;
  const float* src = W1 + (long long)(kt * 32) * N1 + nt * 128;
#pragma unroll
  for (int i = 0; i < 4; ++i) {
    const int idx = i * 256 + t, r = idx >> 5, c4 = idx & 31;
    const float4 v = *(const float4*)(src + (long long)r * N1 + c4 * 4);
    tile[r][c4 * 4 + 0] = v.x; tile[r][c4 * 4 + 1] = v.y;
    tile[r][c4 * 4 + 2] = v.z; tile[r][c4 * 4 + 3] = v.w;
  }
  __syncthreads();
  const long long tb = (long long)(nt * KT + kt) * TILE_E;
#pragma unroll
  for (int i = 0; i < 2; ++i) {
    const int q = i * 256 + t, k16 = q >> 7, col = q & 127;
    ushort8 h, l;
#pragma unroll
    for (int j = 0; j < 8; ++j) {
      const float f = tile[k16 * 8 + j][col];
      const unsigned short hs = f2bf(f);
      h[j] = hs; l[j] = f2bf(f - bf2f(hs));
    }
    *(ushort8*)&Bh[tb + q * 8] = h;
    *(ushort8*)&Bl[tb + q * 8] = l;
  }
}

// ----------------------- GEMM1: split-3 bf16 MFMA ---------------------------
// 128x128 tile, BK=32, 8 waves x (32x64), K-split-4 -> 512 blocks of 512 thr.
// 2 blocks/CU (64KB LDS dbuf) = 16 waves/CU = 4 waves/SIMD.  [r3: 121us]
__global__ __launch_bounds__(512, 4)
void gemm_split3(const unsigned short* __restrict__ Ah, const unsigned short* __restrict__ Al,
                 const unsigned short* __restrict__ Bh, const unsigned short* __restrict__ Bl,
                 const float* __restrict__ b1, float* __restrict__ e1p)
{
  __shared__ unsigned short lds[2][4][TILE_E];   // 64 KB
  const int t = threadIdx.x, lane = t & 63, w = t >> 6;   // w: 0..7
  const int wr = w >> 1, wc = w & 1;                      // wave tile: 32x64
  const int bid = blockIdx.x;
  const int wg = ((bid & 7) << 6) | (bid >> 3);  // XCD chunked swizzle, 512%8==0
  const int ks = wg >> 7;
  const int mt = (wg >> 3) & 15;
  const int nt = wg & 7;
  const int s0 = ks * 94;
  const int nst = (ks == 3) ? 93 : 94;

  const unsigned short* ga0 = Ah + (long long)(mt * KT + s0) * TILE_E;
  const unsigned short* ga1 = Al + (long long)(mt * KT + s0) * TILE_E;
  const unsigned short* ga2 = Bh + (long long)(nt * KT + s0) * TILE_E;
  const unsigned short* ga3 = Bl + (long long)(nt * KT + s0) * TILE_E;

  auto stage = [&](int buf, int s) {   // 512 thr x 16B = 8KB = one array each
    const long long so = (long long)s * TILE_E + t * 8;
    gl_lds16(ga0 + so, &lds[buf][0][t * 8]);
    gl_lds16(ga1 + so, &lds[buf][1][t * 8]);
    gl_lds16(ga2 + so, &lds[buf][2][t * 8]);
    gl_lds16(ga3 + so, &lds[buf][3][t * 8]);
  };

  f32x4 acc[2][4] = {};
  stage(0, 0);
  __syncthreads();
  int buf = 0;
  for (int s = 0; s < nst; ++s) {
    if (s + 1 < nst) stage(buf ^ 1, s + 1);

    const int fr = lane & 15, k16 = lane >> 4;
    bf16x8 ah[2], al[2], bh[4], bl[4];
#pragma unroll
    for (int mf = 0; mf < 2; ++mf) {
      const int row = wr * 32 + mf * 16 + fr;
      ah[mf] = *(const bf16x8*)&lds[buf][0][k16 * 1024 + row * 8];
      al[mf] = *(const bf16x8*)&lds[buf][1][k16 * 1024 + row * 8];
    }
#pragma unroll
    for (int nf = 0; nf < 4; ++nf) {
      const int col = wc * 64 + nf * 16 + fr;
      bh[nf] = *(const bf16x8*)&lds[buf][2][k16 * 1024 + col * 8];
      bl[nf] = *(const bf16x8*)&lds[buf][3][k16 * 1024 + col * 8];
    }
    __builtin_amdgcn_s_setprio(1);
#pragma unroll
    for (int mf = 0; mf < 2; ++mf)
#pragma unroll
      for (int nf = 0; nf < 4; ++nf)
        acc[mf][nf] = __builtin_amdgcn_mfma_f32_16x16x32_bf16(ah[mf], bh[nf], acc[mf][nf], 0, 0, 0);
#pragma unroll
    for (int mf = 0; mf < 2; ++mf)
#pragma unroll
      for (int nf = 0; nf < 4; ++nf)
        acc[mf][nf] = __builtin_amdgcn_mfma_f32_16x16x32_bf16(ah[mf], bl[nf], acc[mf][nf], 0, 0, 0);
#pragma unroll
    for (int mf = 0; mf < 2; ++mf)
#pragma unroll
      for (int nf = 0; nf < 4; ++nf)
        acc[mf][nf] = __builtin_amdgcn_mfma_f32_16x16x32_bf16(al[mf], bh[nf], acc[mf][nf], 0, 0, 0);
    __builtin_amdgcn_s_setprio(0);
    __syncthreads();
    buf ^= 1;
  }

  float* eo = e1p + (long long)ks * MROWS * N1;
#pragma unroll
  for (int mf = 0; mf < 2; ++mf) {
    const int r0 = mt * 128 + wr * 32 + mf * 16 + ((lane >> 4) << 2);
#pragma unroll
    for (int nf = 0; nf < 4; ++nf) {
      const int col = nt * 128 + wc * 64 + nf * 16 + (lane & 15);
      const float bias = (ks == 0) ? b1[col] : 0.0f;
#pragma unroll
      for (int r = 0; r < 4; ++r)
        eo[(long long)(r0 + r) * N1 + col] = acc[mf][nf][r] + bias;
    }
  }
}

// ------------------------ GEMM2 + distances + argmax ------------------------
// r7 head: cooperative LDS reduction of NKS=4 partials (compile-time
// unrolled, coalesced f32x4), GEMM2 from LDS broadcast, distances + argmax.
constexpr int RPB = 8;
constexpr int NKS = 4;

__global__ __launch_bounds__(256, 2)
void head_kernel(const float* __restrict__ e1, const float* __restrict__ W2,
                 const float* __restrict__ b2, const float* __restrict__ cents,
                 float* __restrict__ eOut, float* __restrict__ sOut,
                 float* __restrict__ cOut)
{
  __shared__ float e_red[RPB][N1];        // 32 KB: reduced e1 rows
  __shared__ float cent_s[NCL * 65];      // 26 KB
  __shared__ float e_s[RPB][N2 + 4];
  const int t = threadIdx.x;
  const int r0 = blockIdx.x * RPB;
  constexpr long long PS = (long long)MROWS * N1;

  for (int i = t; i < NCL * N2; i += 256) {
    const int c = i >> 6, d = i & 63;
    cent_s[c * 65 + d] = cents[i];
  }

  // phase 1: reduce NKS partials into e_red (coalesced 1KB/wave loads)
#pragma unroll
  for (int v = 0; v < 8; ++v) {
    const int idx = v * 256 + t;          // 0..2047
    const int row = idx >> 8;             // 0..7
    const int c4  = idx & 255;            // f32x4 slot within row
    const float* src = e1 + (long long)(r0 + row) * N1 + c4 * 4;
    f32x4 x = *(const f32x4*)src;
#pragma unroll
    for (int p = 1; p < NKS; ++p) x += *(const f32x4*)(src + (long long)p * PS);
    *(f32x4*)&e_red[row][c4 * 4] = x;
  }
  __syncthreads();

  // phase 2: GEMM2 from LDS (wave-uniform broadcast reads, conflict-free)
  const int n = t & 63;
  const int rq = t >> 6;
  float acc0 = 0.f, acc1 = 0.f;
  for (int k = 0; k < N1; k += 4) {
    const f32x4 x0 = *(const f32x4*)&e_red[rq][k];
    const f32x4 x1 = *(const f32x4*)&e_red[rq + 4][k];
    const float w0 = W2[(k + 0) * N2 + n];
    const float w1 = W2[(k + 1) * N2 + n];
    const float w2 = W2[(k + 2) * N2 + n];
    const float w3 = W2[(k + 3) * N2 + n];
    acc0 = fmaf(x0[0], w0, acc0); acc0 = fmaf(x0[1], w1, acc0);
    acc0 = fmaf(x0[2], w2, acc0); acc0 = fmaf(x0[3], w3, acc0);
    acc1 = fmaf(x1[0], w0, acc1); acc1 = fmaf(x1[1], w1, acc1);
    acc1 = fmaf(x1[2], w2, acc1); acc1 = fmaf(x1[3], w3, acc1);
  }
  acc0 += b2[n]; acc1 += b2[n];
  eOut[(long long)(r0 + rq) * N2 + n]     = acc0;
  eOut[(long long)(r0 + rq + 4) * N2 + n] = acc1;
  e_s[rq][n]     = acc0;
  e_s[rq + 4][n] = acc1;
  __syncthreads();

  // phase 3: distances + row-normalize + argmax
  const int row = t >> 5;
  const int ci  = t & 31;
  float sum = 0.f, bestv = -1.f;
  int bestc = 0;
  float sv[4] = {0.f, 0.f, 0.f, 0.f};
#pragma unroll
  for (int j = 0; j < 4; ++j) {
    const int c = ci + 32 * j;
    if (c < NCL) {
      float d2 = 0.f;
#pragma unroll 8
      for (int d = 0; d < N2; ++d) {
        const float diff = e_s[row][d] - cent_s[c * 65 + d];
        d2 = fmaf(diff, diff, d2);
      }
      const float su = 1.0f / (1.0f + sqrtf(d2));
      sv[j] = su; sum += su;
      if (su > bestv) { bestv = su; bestc = c; }
    }
  }
#pragma unroll
  for (int off = 1; off < 32; off <<= 1) {
    sum += __shfl_xor(sum, off);
    const float ov = __shfl_xor(bestv, off);
    const int   oc = __shfl_xor(bestc, off);
    if (ov > bestv || (ov == bestv && oc < bestc)) { bestv = ov; bestc = oc; }
  }
  const float inv = 1.0f / sum;
#pragma unroll
  for (int j = 0; j < 4; ++j) {
    const int c = ci + 32 * j;
    if (c < NCL) sOut[(long long)(r0 + row) * NCL + c] = sv[j] * inv;
  }
  if (ci == 0) cOut[r0 + row] = (float)bestc;
}

// --------------------------------- launch -----------------------------------
extern "C" void kernel_launch(void* const* d_in, const int* in_sizes, int n_in,
                              void* d_out, int out_size, void* d_ws, size_t ws_size,
                              hipStream_t stream)
{
  const float* z     = (const float*)d_in[0];
  const float* W1    = (const float*)d_in[1];
  const float* b1    = (const float*)d_in[2];
  const float* W2    = (const float*)d_in[3];
  const float* b2    = (const float*)d_in[4];
  const float* cents = (const float*)d_in[5];
  float* out  = (float*)d_out;
  float* eOut = out;
  float* sOut = out + MROWS * N2;
  float* cOut = out + MROWS * N2 + MROWS * NCL;

  unsigned short* Ah = (unsigned short*)d_ws;
  unsigned short* Al = Ah + AE;
  unsigned short* Bh = Al + AE;
  unsigned short* Bl = Bh + BE;
  float* e1p = (float*)(Bl + BE);

  split_z<<<dim3(KT, MT), 256, 0, stream>>>(z, Ah, Al);
  split_w<<<dim3(KT, NT), 256, 0, stream>>>(W1, Bh, Bl);
  gemm_split3<<<512, 512, 0, stream>>>(Ah, Al, Bh, Bl, b1, e1p);
  head_kernel<<<MROWS / RPB, 256, 0, stream>>>(e1p, W2, b2, cents, eOut, sOut, cOut);
}